// Round 7
// baseline (267.187 us; speedup 1.0000x reference)
//
#include <hip/hip_runtime.h>

// CognitiveLorenzField: 500-step scan over DIM=65536 vectors.
// Exact 2D-subspace reduction: vL_t = p_t*vL0, vJ_t = q_t*vL0 + r_t*vJ0.
//
// R9 -> R10: load-balance the store phase. R6/R9 both ship 800/400 equal
// blocks -> 3.125/1.5625 per CU -> tail CUs carry ceil() blocks = 1.28x
// makespan on the ~24 GB/s/CU store-drain path (the only mechanism not yet
// probed; all others eliminated R3-R9). Fix: flat partition of the
// [500 x 16384] f4 output grid into 1024 equal chunks of 8000 f4 = exactly
// 4 blocks/CU. A chunk spans <=2 t-rows; wave 0 runs the recurrence to t0
// (same op sequence -> bit-identical p,q,r), takes one extra step for t0+1,
// broadcasts 6 floats via LDS; store loop selects per element and re-reads
// vL/vJ from L2 (512 KB resident; 64 MB total reads ~ 2 us of L2 BW).
// Block 1023 (t0=499) stages the full z trajectory during its prologue.

#define DIM 65536
#define STEPS 500
#define DIM4 (DIM / 4)            // 16384 float4 per vector per step
#define CHUNK 8000                // float4 per block: 1024*8000 = 500*16384
#define NBLK 1024                 // exactly 4 blocks per CU on 256 CUs

typedef float vfloat4 __attribute__((ext_vector_type(4)));

__device__ constexpr float ALPHA0 = 1.0f;
__device__ constexpr float BETA_GAME = 0.2f;
__device__ constexpr float GAMMA_C = 0.5f;
__device__ constexpr float SIGMA = 10.0f;
__device__ constexpr float RHO = 28.0f;
__device__ constexpr float LORENZ_BETA = 8.0f / 3.0f;
__device__ constexpr float DT = 0.01f;
__device__ constexpr float EPS = 1e-8f;

// ws layout (floats):
//   [0..63]      per-block partial of vL0.vL0
//   [64..127]    per-block partial of vL0.vJ0

__global__ __launch_bounds__(256) void dot_partials(const vfloat4* __restrict__ vL,
                                                    const vfloat4* __restrict__ vJ,
                                                    float* __restrict__ ws) {
    int tid = threadIdx.x;
    int idx = blockIdx.x * 256 + tid;          // 64 blocks * 256 = 16384 = DIM4
    vfloat4 a = vL[idx];
    vfloat4 b = vJ[idx];
    float sL  = a.x * a.x + a.y * a.y + a.z * a.z + a.w * a.w;
    float sLJ = a.x * b.x + a.y * b.y + a.z * b.z + a.w * b.w;
    #pragma unroll
    for (int off = 32; off > 0; off >>= 1) {
        sL  += __shfl_down(sL,  off, 64);
        sLJ += __shfl_down(sLJ, off, 64);
    }
    __shared__ float redL[4], redLJ[4];
    int wave = tid >> 6;
    if ((tid & 63) == 0) { redL[wave] = sL; redLJ[wave] = sLJ; }
    __syncthreads();
    if (tid == 0) {
        ws[blockIdx.x]      = redL[0] + redL[1] + redL[2] + redL[3];
        ws[64 + blockIdx.x] = redLJ[0] + redLJ[1] + redLJ[2] + redLJ[3];
    }
}

// One recurrence step: updates x,y,z,p,q,r in place. Same op sequence as
// R6/R9 -> bitwise-identical trajectories.
#define REC_STEP()                                                        \
    do {                                                                  \
        float dx = SIGMA * (y - x);                                       \
        float dy = x * (RHO - z) - y;                                     \
        float dz = x * y - LORENZ_BETA * z;                               \
        x += DT * dx;                                                     \
        y += DT * dy;                                                     \
        z += DT * dz;                                                     \
        float alpha = ALPHA0 + GAMMA_C * z;                               \
        float dot = p * (q * L00 + r * L01);                              \
        float nsq = p * p * L00 + EPS;                                    \
        float c   = dot * __builtin_amdgcn_rcpf(nsq);                     \
        float pn = p * (1.0f + DT * (alpha * (c - 1.0f) + BETA_GAME));    \
        float decay = 1.0f - DT * (alpha + BETA_GAME);                    \
        float qn = q * decay + DT * p * (alpha * c + BETA_GAME);          \
        float rn = r * decay;                                             \
        p = pn; q = qn; r = rn;                                           \
    } while (0)

__global__ __launch_bounds__(256) void expand_flat(const vfloat4* __restrict__ vL,
                                                   const vfloat4* __restrict__ vJ,
                                                   const float* __restrict__ ws,
                                                   vfloat4* __restrict__ outL,
                                                   vfloat4* __restrict__ outJ,
                                                   float* __restrict__ outZ) {
    __shared__ float sh[6];                   // p0,q0,r0 (row t0); p1,q1,r1 (row t0+1)
    __shared__ __align__(16) float zbuf[STEPS];

    const int  b     = blockIdx.x;
    const int  tid   = threadIdx.x;
    const long fbase = (long)b * CHUNK;       // flat f4 index of chunk start
    const int  t0    = (int)(fbase >> 14);    // first t-row this chunk touches
    const bool zW    = (b == NBLK - 1);       // t0 == 499: sees all 500 z values

    if (tid < 64) {                           // wave 0 only: recurrence
        // Deterministic 64->1 reduction (same order as before -> same bits).
        float sL  = ws[tid];
        float sLJ = ws[64 + tid];
        #pragma unroll
        for (int off = 32; off > 0; off >>= 1) {
            sL  += __shfl_down(sL,  off, 64);
            sLJ += __shfl_down(sLJ, off, 64);
        }
        const float L00 = __shfl(sL, 0, 64);
        const float L01 = __shfl(sLJ, 0, 64);

        float x = 1.f, y = 1.f, z = 1.f;
        float p = 1.f, q = 0.f, r = 1.f;
        // Row t holds the state after t+1 updates: run t0+1 steps.
        for (int t = 0; t <= t0; ++t) {
            REC_STEP();
            if (zW && tid == 0) zbuf[t] = z;
        }
        if (tid == 0) { sh[0] = p; sh[1] = q; sh[2] = r; }
        REC_STEP();                           // state for row t0+1 (may be unused)
        if (tid == 0) { sh[3] = p; sh[4] = q; sh[5] = r; }
    }
    __syncthreads();

    const float p0 = sh[0], q0 = sh[1], r0 = sh[2];
    const float p1 = sh[3], q1 = sh[4], r1 = sh[5];

    if (zW) {                                 // bulk-write z trajectory
        if (tid < STEPS / 4)
            ((vfloat4*)outZ)[tid] = ((const vfloat4*)zbuf)[tid];
    }

    const long rowB = ((long)(t0 + 1)) << 14; // first flat index of row t0+1

    // 31 full iterations + 64-lane tail: 8000 f4 per block, coalesced.
    #pragma unroll 4
    for (int k = 0; k < 31; ++k) {
        long f = fbase + k * 256 + tid;
        bool hi = (f >= rowB);
        float p = hi ? p1 : p0;
        float q = hi ? q1 : q0;
        float r = hi ? r1 : r0;
        int  j = (int)(f & (DIM4 - 1));       // position within the t-row
        vfloat4 a = vL[j];
        vfloat4 v = vJ[j];
        outL[f] = p * a;
        outJ[f] = q * a + r * v;
    }
    if (tid < 64) {                           // tail: idx 7936..7999
        long f = fbase + 31 * 256 + tid;
        bool hi = (f >= rowB);
        float p = hi ? p1 : p0;
        float q = hi ? q1 : q0;
        float r = hi ? r1 : r0;
        int  j = (int)(f & (DIM4 - 1));
        vfloat4 a = vL[j];
        vfloat4 v = vJ[j];
        outL[f] = p * a;
        outJ[f] = q * a + r * v;
    }
}

extern "C" void kernel_launch(void* const* d_in, const int* in_sizes, int n_in,
                              void* d_out, int out_size, void* d_ws, size_t ws_size,
                              hipStream_t stream) {
    const vfloat4* vL = (const vfloat4*)d_in[0];
    const vfloat4* vJ = (const vfloat4*)d_in[1];
    float* out = (float*)d_out;
    float* ws  = (float*)d_ws;

    float* outL = out;                                   // [500 * 65536]
    float* outJ = out + (size_t)STEPS * DIM;             // [500 * 65536]
    float* outZ = out + 2ull * STEPS * DIM;              // [500]

    dot_partials<<<64, 256, 0, stream>>>(vL, vJ, ws);
    expand_flat<<<NBLK, 256, 0, stream>>>(vL, vJ, ws,
                                          (vfloat4*)outL, (vfloat4*)outJ, outZ);
}